// Round 8
// baseline (217.075 us; speedup 1.0000x reference)
//
#include <hip/hip_runtime.h>
#include <hip/hip_bf16.h>

// RBF kernel layer: out[n][m] = exp(-||x_n - c_m||^2)
// N=16384, M=4096, D=512, fp32 in/out.
// Round 8: round-6 fp8 K-loop (measured: only 40us) + REBUILT EPILOGUE
// (measured: 79us, the real bottleneck). After the K-loop the 64KB LDS is
// free: transpose acc through LDS in 4 chunks of 64 rows x 256 cols fp32,
// then store 1KB-contiguous per wave-instruction (was 16 scattered 64B
// segments). Plain stores (no nt -> L2 write-back merges full lines).
// exp2-based epilogue math with hoisted -(xs+cs)*log2e.

#define NN 16384
#define MM 4096
#define DD 512
#define NT 8  // K-tiles of BK=64

typedef float f32x4 __attribute__((ext_vector_type(4)));
typedef long i64x2 __attribute__((ext_vector_type(2)));

__device__ __forceinline__ void async16(const void* g, void* l) {
  __builtin_amdgcn_global_load_lds(
      (const __attribute__((address_space(1))) void*)g,
      (__attribute__((address_space(3))) void*)l, 16, 0, 0);
}

#define MFMA8(a, b, c) __builtin_amdgcn_mfma_f32_16x16x32_fp8_fp8(a, b, c, 0, 0, 0)

// ---------------------------------------------------------------------------
// Prep: fp32 row -> fp8 e4m3 (row bytes packed (kt, fq)-major: byte =
// kt*64 + fq*16 + ks*8 + e for element k = kt*64 + ks*32 + fq*8 + e) +
// exact fp32 squared norm. One wave per row.
// ---------------------------------------------------------------------------
__global__ __launch_bounds__(256) void prep_fp8(
    const float* __restrict__ x, const float* __restrict__ c,
    unsigned char* __restrict__ x8, unsigned char* __restrict__ c8,
    float* __restrict__ xsq, float* __restrict__ csq) {
  const int w = threadIdx.x >> 6;
  const int lane = threadIdx.x & 63;
  int row = blockIdx.x * 4 + w;
  const float* src = x;
  unsigned char* dst = x8;
  float* sq = xsq;
  if (row >= NN) {
    row -= NN;
    src = c; dst = c8; sq = csq;
    if (row >= MM) return;
  }
  const float* p = src + (size_t)row * DD + lane * 8;
  float4 v0 = *(const float4*)p;
  float4 v1 = *(const float4*)(p + 4);
  float vv[8] = {v0.x, v0.y, v0.z, v0.w, v1.x, v1.y, v1.z, v1.w};
  float s = 0.f;
#pragma unroll
  for (int j = 0; j < 8; ++j) s += vv[j] * vv[j];
  int pk0 = __builtin_amdgcn_cvt_pk_fp8_f32(vv[0], vv[1], 0, false);
  int pk1 = __builtin_amdgcn_cvt_pk_fp8_f32(vv[2], vv[3], 0, false);
  int pk2 = __builtin_amdgcn_cvt_pk_fp8_f32(vv[4], vv[5], 0, false);
  int pk3 = __builtin_amdgcn_cvt_pk_fp8_f32(vv[6], vv[7], 0, false);
  uint2 wrd;
  wrd.x = (unsigned)(pk0 & 0xFFFF) | ((unsigned)pk1 << 16);
  wrd.y = (unsigned)(pk2 & 0xFFFF) | ((unsigned)pk3 << 16);
  const int db = ((lane >> 3) << 6) + ((lane & 3) << 4) + (((lane >> 2) & 1) << 3);
  *(uint2*)(dst + (size_t)row * DD + db) = wrd;
#pragma unroll
  for (int o = 32; o >= 1; o >>= 1) s += __shfl_down(s, o);
  if (lane == 0) sq[row] = s;
}

// ---------------------------------------------------------------------------
// 256x256 8-phase fp8 GEMM (round-6 structure; see r6 FIFO audit) + LDS-
// transposed chunked epilogue.
//
// Epilogue: 4 chunks of 64 block-rows (ck: rows ck*64..ck*64+63; owners =
// waves with wr==ck>>1, local m = (ck&1)*4+ml). LDS float layout: byte =
// lr*1024 + ((g+lr)&63)*16, g = wc*16+n*4+fq (write), g = lane (read).
// Conflict floor check (b128 = 8 clk min): bank-group = (g+lr) mod 8;
// write: (n*4+fq+fr) mod 8 -> 8 lanes/residue; read: (lane+lr) mod 8 ->
// 8 lanes/residue. Both at floor. Stores: lane l covers cols 4l..4l+3 ->
// 64 lanes x 16B = 1KB contiguous per instruction.
// ---------------------------------------------------------------------------
__global__ __launch_bounds__(512, 2) void rbf_gemm(
    const unsigned char* __restrict__ x8, const unsigned char* __restrict__ c8,
    const float* __restrict__ xsq, const float* __restrict__ csq,
    float* __restrict__ out) {
  __shared__ __attribute__((aligned(16))) unsigned char smem[65536];
  // [0,32768): sX[2][16384]; [32768,65536): sC[2][16384]; epilogue: all 64KB.

  const int t = threadIdx.x;
  const int w = t >> 6;
  const int lane = t & 63;
  const int fr = lane & 15;
  const int fq = lane >> 4;
  const int wr = w >> 2;  // x-row half (0..1)
  const int wc = w & 3;   // c-col quarter (0..3)

  const int bid = blockIdx.x;
  const int a = bid & 7, p = bid >> 3;
  const int x0 = ((a << 3) + (p >> 4)) << 8;
  const int c0 = (p & 15) << 8;

  // staging addressing (linear LDS dest, inverse-swizzled global source)
  const int w3 = w & 3;
  const int isX = (w < 4);
  const int rr = 2 * (lane >> 3) + ((lane >> 2) & 1);
  const int ff = (lane & 3) ^ ((lane >> 3) & 3);
  const unsigned char* gsrc =
      (isX ? x8 : c8) +
      (size_t)((isX ? x0 : c0) + 16 * w3 + rr) * DD + ff * 16;
  char* lbase = (char*)smem + (isX ? 0 : 32768) + w3 * 1024;

#define STAGE(buf, i, kt) \
  async16(gsrc + (size_t)(i) * 64 * DD + (kt) * 64, \
          lbase + ((buf) << 14) + (i) * 4096)

  // ds_read addressing: byte = row*64 + 16*(fq ^ ((fr>>1)&3))
  const int sxor = (fq ^ ((fr >> 1) & 3)) << 4;
  const int rcb = (wc * 64 + fr) * 64;
  const int rxb = (wr * 128 + fr) * 64;

  f32x4 acc[8][4];
#pragma unroll
  for (int m = 0; m < 8; ++m)
#pragma unroll
    for (int n = 0; n < 4; ++n) acc[m][n] = (f32x4){0.f, 0.f, 0.f, 0.f};

  // --- prologue: tile0 all 4 issues + tile1 XC0, XC2 ---
  STAGE(0, 0, 0); STAGE(0, 1, 0); STAGE(0, 2, 0); STAGE(0, 3, 0);
  STAGE(1, 0, 1); STAGE(1, 2, 1);
  asm volatile("s_waitcnt vmcnt(2)" ::: "memory");
  __builtin_amdgcn_s_barrier();
  __builtin_amdgcn_sched_barrier(0);

#define DOMFMA(qq, mm)                                                   \
  _Pragma("unroll") for (int n = 0; n < 4; ++n) {                        \
    acc[2 * (qq) + (mm)][n] = MFMA8(cf[n][0], xq[mm][0], acc[2 * (qq) + (mm)][n]); \
    acc[2 * (qq) + (mm)][n] = MFMA8(cf[n][1], xq[mm][1], acc[2 * (qq) + (mm)][n]); \
  }

#pragma unroll 1
  for (int u = 0; u < NT; ++u) {
    const int cur = u & 1;
    const char* bX = (const char*)smem + (cur << 14);
    const char* bC = (const char*)smem + 32768 + (cur << 14);
    i64x2 cf[4], xq[2];
#pragma unroll
    for (int q = 0; q < 4; ++q) {
      if (q == 0) {
#pragma unroll
        for (int n = 0; n < 4; ++n)
          cf[n] = *(const i64x2*)(bC + rcb + n * 1024 + sxor);
      }
#pragma unroll
      for (int mm = 0; mm < 2; ++mm)
        xq[mm] = *(const i64x2*)(bX + rxb + (2 * q + mm) * 1024 + sxor);
      if (q == 0 && u + 1 < NT) STAGE(cur ^ 1, 1, u + 1);
      if (q == 1 && u + 1 < NT) STAGE(cur ^ 1, 3, u + 1);
      if (q == 2 && u + 2 < NT) STAGE(cur, 0, u + 2);
      if (q == 3 && u + 2 < NT) STAGE(cur, 2, u + 2);
      __builtin_amdgcn_s_barrier();
      asm volatile("s_waitcnt lgkmcnt(0)" ::: "memory");
      __builtin_amdgcn_s_setprio(1);
      DOMFMA(q, 0);
      DOMFMA(q, 1);
      __builtin_amdgcn_s_setprio(0);
      if (q == 3) {
        if (u < NT - 2)
          asm volatile("s_waitcnt vmcnt(2)" ::: "memory");
        else if (u == NT - 2)
          asm volatile("s_waitcnt vmcnt(0)" ::: "memory");
      }
      __builtin_amdgcn_s_barrier();
      if (q == 3) __builtin_amdgcn_sched_barrier(0);
    }
  }

  // --- epilogue: chunked LDS transpose -> contiguous 1KB row stores ---
  // d = xs + cs - 2*cr; out = exp(-max(d,0)) = min(exp2(fma(cr, 2*l2e,
  // -(xs+cs)*l2e)), 1).
  float* eb = (float*)smem;
  const float l2e = 1.4426950408889634f;
  const f32x4 csv4 = *(const f32x4*)(csq + c0 + (lane << 2));
  float csl[4];
#pragma unroll
  for (int j = 0; j < 4; ++j) csl[j] = -csv4[j] * l2e;

#pragma unroll 1
  for (int ck = 0; ck < 4; ++ck) {
    __builtin_amdgcn_s_barrier();  // prior reads of smem complete
    if (wr == (ck >> 1)) {
      const int mb = (ck & 1) << 2;
#pragma unroll
      for (int ml = 0; ml < 4; ++ml) {
        const int lr = (ml << 4) + fr;
#pragma unroll
        for (int n = 0; n < 4; ++n) {
          const int g = (wc << 4) + (n << 2) + fq;
          *(f32x4*)((char*)eb + lr * 1024 + (((g + lr) & 63) << 4)) =
              acc[mb + ml][n];
        }
      }
    }
    __builtin_amdgcn_s_barrier();  // chunk fully written
    const int growb = x0 + (ck << 6) + (w << 3);
#pragma unroll
    for (int ri = 0; ri < 8; ++ri) {
      const int lr = (w << 3) + ri;
      const f32x4 cr =
          *(const f32x4*)((char*)eb + lr * 1024 + (((lane + lr) & 63) << 4));
      const float xsl = -xsq[growb + ri] * l2e;
      f32x4 v;
#pragma unroll
      for (int j = 0; j < 4; ++j) {
        const float arg = __builtin_fmaf(cr[j], 2.0f * l2e, xsl + csl[j]);
        v[j] = fminf(__builtin_exp2f(arg), 1.0f);
      }
      *(f32x4*)(out + (size_t)(growb + ri) * MM + c0 + (lane << 2)) = v;
    }
  }
}

// ---------------------------------------------------------------------------
// Fallback (ws too small): direct tiled fp32 distance kernel.
// ---------------------------------------------------------------------------
__global__ void rbf_naive(const float* __restrict__ x,
                          const float* __restrict__ c,
                          float* __restrict__ out) {
  __shared__ float sx[16][17], sc[16][17];
  const int tx = threadIdx.x, ty = threadIdx.y;
  const int row = blockIdx.y * 16 + ty;
  const int colb = blockIdx.x * 16;
  float d = 0.f;
  for (int k0 = 0; k0 < DD; k0 += 16) {
    sx[ty][tx] = x[(size_t)row * DD + k0 + tx];
    sc[ty][tx] = c[(size_t)(colb + ty) * DD + k0 + tx];
    __syncthreads();
#pragma unroll
    for (int k = 0; k < 16; ++k) {
      float diff = sx[ty][k] - sc[tx][k];
      d += diff * diff;
    }
    __syncthreads();
  }
  out[(size_t)row * MM + colb + tx] = __expf(-d);
}

extern "C" void kernel_launch(void* const* d_in, const int* in_sizes, int n_in,
                              void* d_out, int out_size, void* d_ws,
                              size_t ws_size, hipStream_t stream) {
  const float* x = (const float*)d_in[0];
  const float* c = (const float*)d_in[1];
  float* out = (float*)d_out;

  char* ws = (char*)d_ws;
  unsigned char* x8 = (unsigned char*)ws;
  unsigned char* c8 = x8 + (size_t)NN * DD;
  float* xsq = (float*)(c8 + (size_t)MM * DD);
  float* csq = xsq + NN;
  const size_t need = (size_t)((char*)(csq + MM) - ws);

  if (ws_size < need) {
    dim3 grid(MM / 16, NN / 16), block(16, 16);
    rbf_naive<<<grid, block, 0, stream>>>(x, c, out);
    return;
  }

  prep_fp8<<<(NN + MM) / 4, 256, 0, stream>>>(x, c, x8, c8, xsq, csq);
  rbf_gemm<<<(NN / 256) * (MM / 256), 512, 0, stream>>>(x8, c8, xsq, csq, out);
}

// Round 9
// 108.001 us; speedup vs baseline: 2.0099x; 2.0099x over previous
//
#include <hip/hip_runtime.h>
#include <hip/hip_bf16.h>

// RBF kernel layer: out[n][m] = exp(-||x_n - c_m||^2)
// N=16384, M=4096, D=512, fp32 in/out.
// Round 9: round-8 kernel with the rule-#20 fix: the epilogue chunk loop is
// now FULLY UNROLLED so all acc[] indices are compile-time constants (r8's
// "#pragma unroll 1" made acc runtime-indexed -> 128 floats/thread spilled
// to scratch -> WRITE_SIZE 3x output, 217us). Everything else identical:
// fp8 8-phase K-loop (40us measured) + LDS-transposed contiguous-store
// epilogue (1KB per wave-instruction), exp2 math.

#define NN 16384
#define MM 4096
#define DD 512
#define NT 8  // K-tiles of BK=64

typedef float f32x4 __attribute__((ext_vector_type(4)));
typedef long i64x2 __attribute__((ext_vector_type(2)));

__device__ __forceinline__ void async16(const void* g, void* l) {
  __builtin_amdgcn_global_load_lds(
      (const __attribute__((address_space(1))) void*)g,
      (__attribute__((address_space(3))) void*)l, 16, 0, 0);
}

#define MFMA8(a, b, c) __builtin_amdgcn_mfma_f32_16x16x32_fp8_fp8(a, b, c, 0, 0, 0)

// ---------------------------------------------------------------------------
// Prep: fp32 row -> fp8 e4m3 (row bytes packed (kt, fq)-major: byte =
// kt*64 + fq*16 + ks*8 + e for element k = kt*64 + ks*32 + fq*8 + e) +
// exact fp32 squared norm. One wave per row.
// ---------------------------------------------------------------------------
__global__ __launch_bounds__(256) void prep_fp8(
    const float* __restrict__ x, const float* __restrict__ c,
    unsigned char* __restrict__ x8, unsigned char* __restrict__ c8,
    float* __restrict__ xsq, float* __restrict__ csq) {
  const int w = threadIdx.x >> 6;
  const int lane = threadIdx.x & 63;
  int row = blockIdx.x * 4 + w;
  const float* src = x;
  unsigned char* dst = x8;
  float* sq = xsq;
  if (row >= NN) {
    row -= NN;
    src = c; dst = c8; sq = csq;
    if (row >= MM) return;
  }
  const float* p = src + (size_t)row * DD + lane * 8;
  float4 v0 = *(const float4*)p;
  float4 v1 = *(const float4*)(p + 4);
  float vv[8] = {v0.x, v0.y, v0.z, v0.w, v1.x, v1.y, v1.z, v1.w};
  float s = 0.f;
#pragma unroll
  for (int j = 0; j < 8; ++j) s += vv[j] * vv[j];
  int pk0 = __builtin_amdgcn_cvt_pk_fp8_f32(vv[0], vv[1], 0, false);
  int pk1 = __builtin_amdgcn_cvt_pk_fp8_f32(vv[2], vv[3], 0, false);
  int pk2 = __builtin_amdgcn_cvt_pk_fp8_f32(vv[4], vv[5], 0, false);
  int pk3 = __builtin_amdgcn_cvt_pk_fp8_f32(vv[6], vv[7], 0, false);
  uint2 wrd;
  wrd.x = (unsigned)(pk0 & 0xFFFF) | ((unsigned)pk1 << 16);
  wrd.y = (unsigned)(pk2 & 0xFFFF) | ((unsigned)pk3 << 16);
  const int db = ((lane >> 3) << 6) + ((lane & 3) << 4) + (((lane >> 2) & 1) << 3);
  *(uint2*)(dst + (size_t)row * DD + db) = wrd;
#pragma unroll
  for (int o = 32; o >= 1; o >>= 1) s += __shfl_down(s, o);
  if (lane == 0) sq[row] = s;
}

// ---------------------------------------------------------------------------
// 256x256 8-phase fp8 GEMM (round-6 structure; see r6 FIFO audit) + LDS-
// transposed chunked epilogue (round-8 layout; all indices now static).
//
// Epilogue: 4 chunks of 64 block-rows (ck: rows ck*64..ck*64+63; owners =
// waves with wr==ck>>1, local m = (ck&1)*4+ml). LDS float layout: byte =
// lr*1024 + ((g+lr)&63)*16, g = wc*16+n*4+fq (write), g = lane (read).
// Write: (n*4+fq+fr) mod 8 -> 8 lanes/bank-group; read: (lane+lr) mod 8 ->
// 8 lanes/bank-group; both at the b128 floor. Stores: lane l covers cols
// 4l..4l+3 -> 64 lanes x 16B = 1KB contiguous per instruction.
// ---------------------------------------------------------------------------
__global__ __launch_bounds__(512, 2) void rbf_gemm(
    const unsigned char* __restrict__ x8, const unsigned char* __restrict__ c8,
    const float* __restrict__ xsq, const float* __restrict__ csq,
    float* __restrict__ out) {
  __shared__ __attribute__((aligned(16))) unsigned char smem[65536];
  // [0,32768): sX[2][16384]; [32768,65536): sC[2][16384]; epilogue: all 64KB.

  const int t = threadIdx.x;
  const int w = t >> 6;
  const int lane = t & 63;
  const int fr = lane & 15;
  const int fq = lane >> 4;
  const int wr = w >> 2;  // x-row half (0..1)
  const int wc = w & 3;   // c-col quarter (0..3)

  const int bid = blockIdx.x;
  const int a = bid & 7, p = bid >> 3;
  const int x0 = ((a << 3) + (p >> 4)) << 8;
  const int c0 = (p & 15) << 8;

  // staging addressing (linear LDS dest, inverse-swizzled global source)
  const int w3 = w & 3;
  const int isX = (w < 4);
  const int rr = 2 * (lane >> 3) + ((lane >> 2) & 1);
  const int ff = (lane & 3) ^ ((lane >> 3) & 3);
  const unsigned char* gsrc =
      (isX ? x8 : c8) +
      (size_t)((isX ? x0 : c0) + 16 * w3 + rr) * DD + ff * 16;
  char* lbase = (char*)smem + (isX ? 0 : 32768) + w3 * 1024;

#define STAGE(buf, i, kt) \
  async16(gsrc + (size_t)(i) * 64 * DD + (kt) * 64, \
          lbase + ((buf) << 14) + (i) * 4096)

  // ds_read addressing: byte = row*64 + 16*(fq ^ ((fr>>1)&3))
  const int sxor = (fq ^ ((fr >> 1) & 3)) << 4;
  const int rcb = (wc * 64 + fr) * 64;
  const int rxb = (wr * 128 + fr) * 64;

  f32x4 acc[8][4];
#pragma unroll
  for (int m = 0; m < 8; ++m)
#pragma unroll
    for (int n = 0; n < 4; ++n) acc[m][n] = (f32x4){0.f, 0.f, 0.f, 0.f};

  // --- prologue: tile0 all 4 issues + tile1 XC0, XC2 ---
  STAGE(0, 0, 0); STAGE(0, 1, 0); STAGE(0, 2, 0); STAGE(0, 3, 0);
  STAGE(1, 0, 1); STAGE(1, 2, 1);
  asm volatile("s_waitcnt vmcnt(2)" ::: "memory");
  __builtin_amdgcn_s_barrier();
  __builtin_amdgcn_sched_barrier(0);

#define DOMFMA(qq, mm)                                                   \
  _Pragma("unroll") for (int n = 0; n < 4; ++n) {                        \
    acc[2 * (qq) + (mm)][n] = MFMA8(cf[n][0], xq[mm][0], acc[2 * (qq) + (mm)][n]); \
    acc[2 * (qq) + (mm)][n] = MFMA8(cf[n][1], xq[mm][1], acc[2 * (qq) + (mm)][n]); \
  }

#pragma unroll 1
  for (int u = 0; u < NT; ++u) {
    const int cur = u & 1;
    const char* bX = (const char*)smem + (cur << 14);
    const char* bC = (const char*)smem + 32768 + (cur << 14);
    i64x2 cf[4], xq[2];
#pragma unroll
    for (int q = 0; q < 4; ++q) {
      if (q == 0) {
#pragma unroll
        for (int n = 0; n < 4; ++n)
          cf[n] = *(const i64x2*)(bC + rcb + n * 1024 + sxor);
      }
#pragma unroll
      for (int mm = 0; mm < 2; ++mm)
        xq[mm] = *(const i64x2*)(bX + rxb + (2 * q + mm) * 1024 + sxor);
      if (q == 0 && u + 1 < NT) STAGE(cur ^ 1, 1, u + 1);
      if (q == 1 && u + 1 < NT) STAGE(cur ^ 1, 3, u + 1);
      if (q == 2 && u + 2 < NT) STAGE(cur, 0, u + 2);
      if (q == 3 && u + 2 < NT) STAGE(cur, 2, u + 2);
      __builtin_amdgcn_s_barrier();
      asm volatile("s_waitcnt lgkmcnt(0)" ::: "memory");
      __builtin_amdgcn_s_setprio(1);
      DOMFMA(q, 0);
      DOMFMA(q, 1);
      __builtin_amdgcn_s_setprio(0);
      if (q == 3) {
        if (u < NT - 2)
          asm volatile("s_waitcnt vmcnt(2)" ::: "memory");
        else if (u == NT - 2)
          asm volatile("s_waitcnt vmcnt(0)" ::: "memory");
      }
      __builtin_amdgcn_s_barrier();
      if (q == 3) __builtin_amdgcn_sched_barrier(0);
    }
  }

  // --- epilogue: chunked LDS transpose -> contiguous 1KB row stores.
  // FULLY UNROLLED (static acc indices; rule #20). ---
  float* eb = (float*)smem;
  const float l2e = 1.4426950408889634f;
  const f32x4 csv4 = *(const f32x4*)(csq + c0 + (lane << 2));
  float csl[4];
#pragma unroll
  for (int j = 0; j < 4; ++j) csl[j] = -csv4[j] * l2e;

#pragma unroll
  for (int ck = 0; ck < 4; ++ck) {
    __builtin_amdgcn_s_barrier();  // prior reads of smem complete
    if (wr == (ck >> 1)) {
      const int mb = (ck & 1) << 2;
#pragma unroll
      for (int ml = 0; ml < 4; ++ml) {
        const int lr = (ml << 4) + fr;
#pragma unroll
        for (int n = 0; n < 4; ++n) {
          const int g = (wc << 4) + (n << 2) + fq;
          *(f32x4*)((char*)eb + lr * 1024 + (((g + lr) & 63) << 4)) =
              acc[mb + ml][n];
        }
      }
    }
    __builtin_amdgcn_s_barrier();  // chunk fully written
    const int growb = x0 + (ck << 6) + (w << 3);
#pragma unroll
    for (int ri = 0; ri < 8; ++ri) {
      const int lr = (w << 3) + ri;
      const f32x4 cr =
          *(const f32x4*)((char*)eb + lr * 1024 + (((lane + lr) & 63) << 4));
      const float xsl = -xsq[growb + ri] * l2e;
      f32x4 v;
#pragma unroll
      for (int j = 0; j < 4; ++j) {
        const float arg = __builtin_fmaf(cr[j], 2.0f * l2e, xsl + csl[j]);
        v[j] = fminf(__builtin_exp2f(arg), 1.0f);
      }
      *(f32x4*)(out + (size_t)(growb + ri) * MM + c0 + (lane << 2)) = v;
    }
  }
}

// ---------------------------------------------------------------------------
// Fallback (ws too small): direct tiled fp32 distance kernel.
// ---------------------------------------------------------------------------
__global__ void rbf_naive(const float* __restrict__ x,
                          const float* __restrict__ c,
                          float* __restrict__ out) {
  __shared__ float sx[16][17], sc[16][17];
  const int tx = threadIdx.x, ty = threadIdx.y;
  const int row = blockIdx.y * 16 + ty;
  const int colb = blockIdx.x * 16;
  float d = 0.f;
  for (int k0 = 0; k0 < DD; k0 += 16) {
    sx[ty][tx] = x[(size_t)row * DD + k0 + tx];
    sc[ty][tx] = c[(size_t)(colb + ty) * DD + k0 + tx];
    __syncthreads();
#pragma unroll
    for (int k = 0; k < 16; ++k) {
      float diff = sx[ty][k] - sc[tx][k];
      d += diff * diff;
    }
    __syncthreads();
  }
  out[(size_t)row * MM + colb + tx] = __expf(-d);
}

extern "C" void kernel_launch(void* const* d_in, const int* in_sizes, int n_in,
                              void* d_out, int out_size, void* d_ws,
                              size_t ws_size, hipStream_t stream) {
  const float* x = (const float*)d_in[0];
  const float* c = (const float*)d_in[1];
  float* out = (float*)d_out;

  char* ws = (char*)d_ws;
  unsigned char* x8 = (unsigned char*)ws;
  unsigned char* c8 = x8 + (size_t)NN * DD;
  float* xsq = (float*)(c8 + (size_t)MM * DD);
  float* csq = xsq + NN;
  const size_t need = (size_t)((char*)(csq + MM) - ws);

  if (ws_size < need) {
    dim3 grid(MM / 16, NN / 16), block(16, 16);
    rbf_naive<<<grid, block, 0, stream>>>(x, c, out);
    return;
  }

  prep_fp8<<<(NN + MM) / 4, 256, 0, stream>>>(x, c, x8, c8, xsq, csq);
  rbf_gemm<<<(NN / 256) * (MM / 256), 512, 0, stream>>>(x8, c8, xsq, csq, out);
}

// Round 10
// 99.585 us; speedup vs baseline: 2.1798x; 1.0845x over previous
//
#include <hip/hip_runtime.h>
#include <hip/hip_bf16.h>

// RBF kernel layer: out[n][m] = exp(-||x_n - c_m||^2)
// N=16384, M=4096, D=512, fp32 in/out.
// Round 10: PERSISTENT DUAL-BANK fp8 GEMM with stores interleaved into the
// K-loop. r7 probe: K-loop = 40us; E = ~60us; occupancy showed 1 block/CU =>
// K and E were strictly serial. This kernel overlaps them inside one block:
// BM=128 x BN=256 tile, 8 waves, two acc banks (64 VGPR each); while bank N
// accumulates output-tile ot, bank O (tile ot-1) is exp'd + stored, 2 store
// instrs per K-tile, FIFO-positioned so every boundary wait is vmcnt(4).
// All epilogue-side global loads are inline-asm (manual FIFO control).

#define NN 16384
#define MM 4096
#define DD 512

typedef float f32x4 __attribute__((ext_vector_type(4)));
typedef long i64x2 __attribute__((ext_vector_type(2)));

__device__ __forceinline__ void async16(const void* g, void* l) {
  __builtin_amdgcn_global_load_lds(
      (const __attribute__((address_space(1))) void*)g,
      (__attribute__((address_space(3))) void*)l, 16, 0, 0);
}

#define MFMA8(a, b, c) __builtin_amdgcn_mfma_f32_16x16x32_fp8_fp8(a, b, c, 0, 0, 0)
#define WAITVM(n) asm volatile("s_waitcnt vmcnt(" #n ")" ::: "memory")
#define GLD4(dst, addr) \
  asm volatile("global_load_dwordx4 %0, %1, off" : "=v"(dst) : "v"(addr))
#define GLD1(dst, addr) \
  asm volatile("global_load_dword %0, %1, off" : "=v"(dst) : "v"(addr))

// ---------------------------------------------------------------------------
// Prep: fp32 row -> fp8 e4m3 (row bytes packed (kt, fq)-major: byte =
// kt*64 + fq*16 + ks*8 + e for element k = kt*64 + ks*32 + fq*8 + e) +
// exact fp32 squared norm. One wave per row.
// ---------------------------------------------------------------------------
__global__ __launch_bounds__(256) void prep_fp8(
    const float* __restrict__ x, const float* __restrict__ c,
    unsigned char* __restrict__ x8, unsigned char* __restrict__ c8,
    float* __restrict__ xsq, float* __restrict__ csq) {
  const int w = threadIdx.x >> 6;
  const int lane = threadIdx.x & 63;
  int row = blockIdx.x * 4 + w;
  const float* src = x;
  unsigned char* dst = x8;
  float* sq = xsq;
  if (row >= NN) {
    row -= NN;
    src = c; dst = c8; sq = csq;
    if (row >= MM) return;
  }
  const float* p = src + (size_t)row * DD + lane * 8;
  float4 v0 = *(const float4*)p;
  float4 v1 = *(const float4*)(p + 4);
  float vv[8] = {v0.x, v0.y, v0.z, v0.w, v1.x, v1.y, v1.z, v1.w};
  float s = 0.f;
#pragma unroll
  for (int j = 0; j < 8; ++j) s += vv[j] * vv[j];
  int pk0 = __builtin_amdgcn_cvt_pk_fp8_f32(vv[0], vv[1], 0, false);
  int pk1 = __builtin_amdgcn_cvt_pk_fp8_f32(vv[2], vv[3], 0, false);
  int pk2 = __builtin_amdgcn_cvt_pk_fp8_f32(vv[4], vv[5], 0, false);
  int pk3 = __builtin_amdgcn_cvt_pk_fp8_f32(vv[6], vv[7], 0, false);
  uint2 wrd;
  wrd.x = (unsigned)(pk0 & 0xFFFF) | ((unsigned)pk1 << 16);
  wrd.y = (unsigned)(pk2 & 0xFFFF) | ((unsigned)pk3 << 16);
  const int db = ((lane >> 3) << 6) + ((lane & 3) << 4) + (((lane >> 2) & 1) << 3);
  *(uint2*)(dst + (size_t)row * DD + db) = wrd;
#pragma unroll
  for (int o = 32; o >= 1; o >>= 1) s += __shfl_down(s, o);
  if (lane == 0) sq[row] = s;
}

// ---------------------------------------------------------------------------
// Persistent GEMM. 512 blocks; block = x-panel (128 rows) x c-strip (4
// c-blocks of 256 cols), 32 K-tiles continuous (V = ot*8+kk). 8 waves:
// wr = w>>2 (x 64-half), wc = w&3 (c 64-quarter); per wave 4x4 16x16 frags.
// A-operand = centroid, B = x. Acc banks aA/aB alternate per ot; bank being
// accumulated never aliases bank being stored.
//
// LDS 48KB: X[2][128][64B] @0/8192; C[2][256][64B] @16384/32768.
// fp8 swizzle (r6-proven): byte = row*64 + 16*(fq ^ ((row>>1)&3)) + ks*8;
// staging = linear LDS dest + inverse-swizzled global source.
//
// Per-tile schedule (2 barriers/phase, r6-proven):
//   q0: ds cf x4 + xq; stage X(V+1)->buf (V+1)&1; [kk==6: 4 asm csq loads]
//   q1: ds xq; stage C0(V+2)->buf V&1; [store frag 2*(V&7) of old bank]
//   q2: ds xq; stage C1(V+2)
//   q3: ds xq; [store frag 2*(V&7)+1]; MFMA; vmcnt(N); barrier; sched_barrier
// FIFO at boundary of tile V: [X(V+1), (cs x4), C0(V+2), st, C1(V+2), st]
// -> retire X(V+1) (C(V+1) is FIFO-older, retired with it):
//   N = 4 (stores on), 2 (ot0), 8 (kk==6 w/ cs), 6 (V=30), 4 (V=31: retires
//   csB for the tail). Stores ~2 tiles old must retire at each boundary --
//   that IS the store-drain pacing (L2-accept latency << tile time).
// csq/xsq loads are inline asm => exact FIFO position, no compiler vmcnt(0);
// every tile ends with sched_barrier(0) so no VALU hoists past the waits.
// ---------------------------------------------------------------------------
__global__ __launch_bounds__(512, 2) void rbf_gemm(
    const unsigned char* __restrict__ x8, const unsigned char* __restrict__ c8,
    const float* __restrict__ xsq, const float* __restrict__ csq,
    float* __restrict__ out) {
  __shared__ __attribute__((aligned(16))) unsigned char smem[49152];

  const int t = threadIdx.x;
  const int w = t >> 6;
  const int lane = t & 63;
  const int fr = lane & 15;
  const int fq = lane >> 4;
  const int wr = w >> 2;  // x 64-half
  const int wc = w & 3;   // c 64-quarter

  // 512 blocks: XCD a = bid&7; q = bid>>3: x-panel a*16 + (q>>2), strip q&3.
  const int bid = blockIdx.x;
  const int a = bid & 7, qq = bid >> 3;
  const int x0 = ((a << 4) + (qq >> 2)) << 7;
  const int strip = qq & 3;

  // staging addressing: 512 thr x 16B = 8KB/issue (128 rows x 64B).
  // thread t -> row t>>2, dest 16B-slot t&3; inverse-swizzled source slot.
  const int srow = t >> 2;
  const int ssl = ((t & 3) ^ ((t >> 3) & 3)) << 4;
  const unsigned char* gx = x8 + (size_t)(x0 + srow) * DD + ssl;
  const unsigned char* gc = c8 + (size_t)srow * DD + ssl;

#define COFF(v, i)                                                        \
  ((size_t)(((((strip) << 2) + ((v) >> 3)) << 8) + (i) * 128) * DD +      \
   ((v) & 7) * 64)

  // ds_read addressing
  const int sxor = (fq ^ ((fr >> 1) & 3)) << 4;
  const int rcb = (wc * 64 + fr) * 64 + sxor;  // + n*1024
  const int rxb = (wr * 64 + fr) * 64 + sxor;  // + q*1024

  f32x4 aA[4][4], aB[4][4];
  f32x4 csA[4], csB[4];
  float xsr[4];

#define STFRAG(AO, CS, CPRE, S)                                               \
  do {                                                                        \
    f32x4 _v;                                                                 \
    _Pragma("unroll") for (int _j = 0; _j < 4; ++_j) {                        \
      float _t = __builtin_fmaf(                                              \
          AO[(S) >> 2][(S)&3][_j], 2.8853900817779268f,                       \
          __builtin_fmaf(CS[(S)&3][_j], -1.4426950408889634f,                 \
                         xsr[(S) >> 2] * -1.4426950408889634f));              \
      _v[_j] = fminf(__builtin_exp2f(_t), 1.0f);                              \
    }                                                                         \
    *(f32x4*)(out + (size_t)(x0 + wr * 64 + (((S) >> 2) << 4) + fr) * MM +    \
              (CPRE) + wc * 64 + (((S)&3) << 4) + (fq << 2)) = _v;            \
  } while (0)

#define MF4(AN, Q, V)                                                     \
  do {                                                                    \
    _Pragma("unroll") for (int _n = 0; _n < 4; ++_n) {                    \
      f32x4 _c = ((V)&7) == 0 ? (f32x4){0.f, 0.f, 0.f, 0.f} : AN[Q][_n];  \
      _c = MFMA8(cf[_n][0], xq[0], _c);                                   \
      AN[Q][_n] = MFMA8(cf[_n][1], xq[1], _c);                            \
    }                                                                     \
  } while (0)

#define KT(V, AN, AO, CS, SEN, CPRE, CSLD, CSB, CSOT, VMN)                    \
  do {                                                                        \
    const char* bX = (const char*)smem + (((V)&1) << 13);                     \
    const char* bC = (const char*)smem + 16384 + (((V)&1) << 14);             \
    char* dXw = (char*)smem + ((((V) + 1) & 1) << 13) + (w << 10);            \
    char* dCw = (char*)smem + 16384 + (((V)&1) << 14) + (w << 10);            \
    i64x2 cf[4], xq;                                                          \
    cf[0] = *(const i64x2*)(bC + rcb);                                        \
    cf[1] = *(const i64x2*)(bC + rcb + 1024);                                 \
    cf[2] = *(const i64x2*)(bC + rcb + 2048);                                 \
    cf[3] = *(const i64x2*)(bC + rcb + 3072);                                 \
    xq = *(const i64x2*)(bX + rxb);                                           \
    if ((V) + 1 < 32) async16(gx + (((V) + 1) & 7) * 64, dXw);                \
    if (CSLD) {                                                               \
      const float* _cp =                                                      \
          csq + (((strip << 2) + (CSOT)) << 8) + wc * 64 + (fq << 2);         \
      GLD4(CSB[0], _cp);                                                      \
      GLD4(CSB[1], _cp + 16);                                                 \
      GLD4(CSB[2], _cp + 32);                                                 \
      GLD4(CSB[3], _cp + 48);                                                 \
    }                                                                         \
    __builtin_amdgcn_s_barrier();                                             \
    asm volatile("s_waitcnt lgkmcnt(0)" ::: "memory");                        \
    __builtin_amdgcn_s_setprio(1);                                            \
    MF4(AN, 0, V);                                                            \
    __builtin_amdgcn_s_setprio(0);                                            \
    __builtin_amdgcn_s_barrier();                                             \
    xq = *(const i64x2*)(bX + rxb + 1024);                                    \
    if ((V) + 2 < 32) async16(gc + COFF((V) + 2, 0), dCw);                    \
    if (SEN) STFRAG(AO, CS, CPRE, 2 * ((V)&7));                               \
    __builtin_amdgcn_s_barrier();                                             \
    asm volatile("s_waitcnt lgkmcnt(0)" ::: "memory");                        \
    __builtin_amdgcn_s_setprio(1);                                            \
    MF4(AN, 1, V);                                                            \
    __builtin_amdgcn_s_setprio(0);                                            \
    __builtin_amdgcn_s_barrier();                                             \
    xq = *(const i64x2*)(bX + rxb + 2048);                                    \
    if ((V) + 2 < 32) async16(gc + COFF((V) + 2, 1), dCw + 8192);             \
    __builtin_amdgcn_s_barrier();                                             \
    asm volatile("s_waitcnt lgkmcnt(0)" ::: "memory");                        \
    __builtin_amdgcn_s_setprio(1);                                            \
    MF4(AN, 2, V);                                                            \
    __builtin_amdgcn_s_setprio(0);                                            \
    __builtin_amdgcn_s_barrier();                                             \
    xq = *(const i64x2*)(bX + rxb + 3072);                                    \
    if (SEN) STFRAG(AO, CS, CPRE, 2 * ((V)&7) + 1);                           \
    __builtin_amdgcn_s_barrier();                                             \
    asm volatile("s_waitcnt lgkmcnt(0)" ::: "memory");                        \
    __builtin_amdgcn_s_setprio(1);                                            \
    MF4(AN, 3, V);                                                            \
    __builtin_amdgcn_s_setprio(0);                                            \
    WAITVM(VMN);                                                              \
    __builtin_amdgcn_s_barrier();                                             \
    __builtin_amdgcn_sched_barrier(0);                                        \
  } while (0)

  const int CP0 = ((strip << 2) + 0) << 8;
  const int CP1 = ((strip << 2) + 1) << 8;
  const int CP2 = ((strip << 2) + 2) << 8;
  const int CP3 = ((strip << 2) + 3) << 8;

  // --- prologue: asm csq(ot0)/xsq loads, then C(0) x2, X(0), C(1) x2.
  // FIFO: [cs x4, xs x4, C00, C01, X0, C10, C11] -> retire X0: vmcnt(2). ---
  {
    const float* cp = csq + (CP0 + wc * 64 + (fq << 2));
    GLD4(csA[0], cp); GLD4(csA[1], cp + 16);
    GLD4(csA[2], cp + 32); GLD4(csA[3], cp + 48);
    const float* xp = xsq + x0 + wr * 64 + fr;
    GLD1(xsr[0], xp); GLD1(xsr[1], xp + 16);
    GLD1(xsr[2], xp + 32); GLD1(xsr[3], xp + 48);
  }
  async16(gc + COFF(0, 0), (char*)smem + 16384 + (w << 10));
  async16(gc + COFF(0, 1), (char*)smem + 16384 + 8192 + (w << 10));
  async16(gx, (char*)smem + (w << 10));
  async16(gc + COFF(1, 0), (char*)smem + 32768 + (w << 10));
  async16(gc + COFF(1, 1), (char*)smem + 32768 + 8192 + (w << 10));
  WAITVM(2);
  __builtin_amdgcn_s_barrier();
  __builtin_amdgcn_sched_barrier(0);

  // --- 32 K-tiles, fully unrolled (static acc/store indices) ---
  // ot0: fill aA, no stores
  KT(0, aA, aB, csA, 0, CP0, 0, csB, 0, 2);
  KT(1, aA, aB, csA, 0, CP0, 0, csB, 0, 2);
  KT(2, aA, aB, csA, 0, CP0, 0, csB, 0, 2);
  KT(3, aA, aB, csA, 0, CP0, 0, csB, 0, 2);
  KT(4, aA, aB, csA, 0, CP0, 0, csB, 0, 2);
  KT(5, aA, aB, csA, 0, CP0, 0, csB, 0, 2);
  KT(6, aA, aB, csA, 0, CP0, 0, csB, 0, 2);
  KT(7, aA, aB, csA, 0, CP0, 0, csB, 0, 2);
  // ot1: fill aB, store aA (ot0 cols, csA); kk6 prefetch csB(ot1 cols)
  KT(8, aB, aA, csA, 1, CP0, 0, csB, 1, 4);
  KT(9, aB, aA, csA, 1, CP0, 0, csB, 1, 4);
  KT(10, aB, aA, csA, 1, CP0, 0, csB, 1, 4);
  KT(11, aB, aA, csA, 1, CP0, 0, csB, 1, 4);
  KT(12, aB, aA, csA, 1, CP0, 0, csB, 1, 4);
  KT(13, aB, aA, csA, 1, CP0, 0, csB, 1, 4);
  KT(14, aB, aA, csA, 1, CP0, 1, csB, 1, 8);
  KT(15, aB, aA, csA, 1, CP0, 0, csB, 1, 4);
  // ot2: fill aA, store aB (ot1 cols, csB); kk6 prefetch csA(ot2 cols)
  KT(16, aA, aB, csB, 1, CP1, 0, csA, 2, 4);
  KT(17, aA, aB, csB, 1, CP1, 0, csA, 2, 4);
  KT(18, aA, aB, csB, 1, CP1, 0, csA, 2, 4);
  KT(19, aA, aB, csB, 1, CP1, 0, csA, 2, 4);
  KT(20, aA, aB, csB, 1, CP1, 0, csA, 2, 4);
  KT(21, aA, aB, csB, 1, CP1, 0, csA, 2, 4);
  KT(22, aA, aB, csB, 1, CP1, 1, csA, 2, 8);
  KT(23, aA, aB, csB, 1, CP1, 0, csA, 2, 4);
  // ot3: fill aB, store aA (ot2 cols, csA); kk6 prefetch csB(ot3 cols)
  KT(24, aB, aA, csA, 1, CP2, 0, csB, 3, 4);
  KT(25, aB, aA, csA, 1, CP2, 0, csB, 3, 4);
  KT(26, aB, aA, csA, 1, CP2, 0, csB, 3, 4);
  KT(27, aB, aA, csA, 1, CP2, 0, csB, 3, 4);
  KT(28, aB, aA, csA, 1, CP2, 0, csB, 3, 4);
  KT(29, aB, aA, csA, 1, CP2, 0, csB, 3, 4);
  KT(30, aB, aA, csA, 1, CP2, 1, csB, 3, 6);
  KT(31, aB, aA, csA, 1, CP2, 0, csB, 3, 4);  // vmcnt(4) also retires csB

  // --- tail: store aB (ot3 cols, csB) ---
#pragma unroll
  for (int S = 0; S < 16; ++S) STFRAG(aB, csB, CP3, S);
}

// ---------------------------------------------------------------------------
// Fallback (ws too small): direct tiled fp32 distance kernel.
// ---------------------------------------------------------------------------
__global__ void rbf_naive(const float* __restrict__ x,
                          const float* __restrict__ c,
                          float* __restrict__ out) {
  __shared__ float sx[16][17], sc[16][17];
  const int tx = threadIdx.x, ty = threadIdx.y;
  const int row = blockIdx.y * 16 + ty;
  const int colb = blockIdx.x * 16;
  float d = 0.f;
  for (int k0 = 0; k0 < DD; k0 += 16) {
    sx[ty][tx] = x[(size_t)row * DD + k0 + tx];
    sc[ty][tx] = c[(size_t)(colb + ty) * DD + k0 + tx];
    __syncthreads();
#pragma unroll
    for (int k = 0; k < 16; ++k) {
      float diff = sx[ty][k] - sc[tx][k];
      d += diff * diff;
    }
    __syncthreads();
  }
  out[(size_t)row * MM + colb + tx] = __expf(-d);
}

extern "C" void kernel_launch(void* const* d_in, const int* in_sizes, int n_in,
                              void* d_out, int out_size, void* d_ws,
                              size_t ws_size, hipStream_t stream) {
  const float* x = (const float*)d_in[0];
  const float* c = (const float*)d_in[1];
  float* out = (float*)d_out;

  char* ws = (char*)d_ws;
  unsigned char* x8 = (unsigned char*)ws;
  unsigned char* c8 = x8 + (size_t)NN * DD;
  float* xsq = (float*)(c8 + (size_t)MM * DD);
  float* csq = xsq + NN;
  const size_t need = (size_t)((char*)(csq + MM) - ws);

  if (ws_size < need) {
    dim3 grid(MM / 16, NN / 16), block(16, 16);
    rbf_naive<<<grid, block, 0, stream>>>(x, c, out);
    return;
  }

  prep_fp8<<<(NN + MM) / 4, 256, 0, stream>>>(x, c, x8, c8, xsq, csq);
  rbf_gemm<<<512, 512, 0, stream>>>(x8, c8, xsq, csq, out);
}